// Round 3
// baseline (639.057 us; speedup 1.0000x reference)
//
#include <hip/hip_runtime.h>
#include <hip/hip_bf16.h>

typedef __bf16 bf16x8 __attribute__((ext_vector_type(8)));
typedef __bf16 bf16x4 __attribute__((ext_vector_type(4)));
typedef float floatx4 __attribute__((ext_vector_type(4)));

#define B_    4096
#define IN_   2048
#define HID_  4096
#define NC_   1000
#define NCP_  1024

// ---------------------------------------------------------------------------
// Transpose+convert device body: src [R][C] f32 -> dst [c][r] bf16, c range
// [64*by, 64*by+63] (c >= C zero-filled; dst padded). Stride-65 f32 tile:
// phase-1 writes conflict-free, phase-2 reads 2-way (free). 16B stores.
// ---------------------------------------------------------------------------
__device__ __forceinline__ void transpose_cvt_dev(const float* __restrict__ src,
                                                  __bf16* __restrict__ dst,
                                                  int R, int C, int bx, int by,
                                                  float* tile /* >= 64*65 f32 */) {
    const int r0 = bx * 64;
    const int c0 = by * 64;
    const int t  = threadIdx.x;
#pragma unroll
    for (int it = 0; it < 4; ++it) {
        int lin = it * 256 + t;
        int sr = lin >> 4, c4 = lin & 15;
        int cb = c0 + c4 * 4;
        const float* s = src + (size_t)(r0 + sr) * C;
        float4 v;
        if (cb + 3 < C) {
            v = *(const float4*)(s + cb);
        } else {
            v.x = (cb + 0 < C) ? s[cb + 0] : 0.f;
            v.y = (cb + 1 < C) ? s[cb + 1] : 0.f;
            v.z = (cb + 2 < C) ? s[cb + 2] : 0.f;
            v.w = (cb + 3 < C) ? s[cb + 3] : 0.f;
        }
        tile[(c4 * 4 + 0) * 65 + sr] = v.x;
        tile[(c4 * 4 + 1) * 65 + sr] = v.y;
        tile[(c4 * 4 + 2) * 65 + sr] = v.z;
        tile[(c4 * 4 + 3) * 65 + sr] = v.w;
    }
    __syncthreads();
#pragma unroll
    for (int it = 0; it < 2; ++it) {
        int lin = it * 256 + t;                 // 0..511
        int dr = lin >> 3, q8 = lin & 7;
        bf16x8 o;
#pragma unroll
        for (int j = 0; j < 8; ++j) o[j] = (__bf16)tile[dr * 65 + q8 * 8 + j];
        *(bf16x8*)(dst + (size_t)(c0 + dr) * R + r0 + q8 * 8) = o;
    }
}

// ---------------------------------------------------------------------------
// XCD-aware swizzle for a 32x32 tile grid (gemm1 / 128x128 core).
// ---------------------------------------------------------------------------
__device__ __forceinline__ void swizzle32x32(int bid, int& bx, int& by) {
    int xcd = bid & 7;
    int q   = bid >> 3;                         // 0..127
    by = ((xcd >> 2) << 4) + (q & 15);          // patch row: 2 x 16
    bx = ((xcd & 3) << 3) + (q >> 4);           // patch col: 4 x 8
}

// ---------------------------------------------------------------------------
// GEMM core (R2-verified, DO NOT PERTURB): 128x128 block, 4 waves (2x2),
// wave 64x64 as 4x4 MFMA 16x16x32 frags. XOR swizzle: LDS slot (r,c) holds
// global chunk c^(r&7); frag reads use chunk (kk*4+lr)^(lc&7) ->
// SQ_LDS_BANK_CONFLICT == 0 (measured R2/R4/R5/R6/R7, 1074 TF).
// Used by gemm1_fused and gemm_sk. Layer-2 uses gemm2_256 below.
// ---------------------------------------------------------------------------
template <bool RELU, bool OUT_BF16>
__device__ __forceinline__ void gemm_core(const __bf16* __restrict__ A,
                                          const __bf16* __restrict__ Bt,
                                          const float* __restrict__ bias,
                                          void* __restrict__ Cv,
                                          int M, int K, int Nstore,
                                          int bx, int by,
                                          __bf16* sA, __bf16* sB) {
    const int tid   = threadIdx.x;
    const int lane  = tid & 63;
    const int wave  = tid >> 6;
    const int wr    = wave >> 1;
    const int wc    = wave & 1;
    const int mBase = by * 128;
    const int nBase = bx * 128;
    const int lr    = lane >> 4;
    const int lc    = lane & 15;

    floatx4 acc[4][4];
#pragma unroll
    for (int i = 0; i < 4; ++i)
#pragma unroll
        for (int j = 0; j < 4; ++j) acc[i][j] = (floatx4)0.f;

    for (int k0 = 0; k0 < K; k0 += 64) {
#pragma unroll
        for (int it = 0; it < 4; ++it) {
            int lin = it * 256 + tid;
            int r   = lin >> 3;
            int kc  = (lin & 7) ^ (r & 7);          // XOR swizzle
            const __bf16* ga = A  + (size_t)(mBase + r) * K + k0 + kc * 8;
            const __bf16* gb = Bt + (size_t)(nBase + r) * K + k0 + kc * 8;
            __builtin_amdgcn_global_load_lds(
                (__attribute__((address_space(1))) void*)ga,
                (__attribute__((address_space(3))) void*)(sA + lin * 8), 16, 0, 0);
            __builtin_amdgcn_global_load_lds(
                (__attribute__((address_space(1))) void*)gb,
                (__attribute__((address_space(3))) void*)(sB + lin * 8), 16, 0, 0);
        }
        __builtin_amdgcn_s_waitcnt(0);
        __syncthreads();

#pragma unroll
        for (int kk = 0; kk < 2; ++kk) {
            const int sw = (kk * 4 + lr) ^ (lc & 7);   // swizzled chunk
            bf16x8 af[4], bfr[4];
#pragma unroll
            for (int i = 0; i < 4; ++i)
                af[i] = *(const bf16x8*)(sA + (wr * 64 + i * 16 + lc) * 64 + sw * 8);
#pragma unroll
            for (int j = 0; j < 4; ++j)
                bfr[j] = *(const bf16x8*)(sB + (wc * 64 + j * 16 + lc) * 64 + sw * 8);
#pragma unroll
            for (int i = 0; i < 4; ++i)
#pragma unroll
                for (int j = 0; j < 4; ++j)
                    acc[i][j] = __builtin_amdgcn_mfma_f32_16x16x32_bf16(af[i], bfr[j], acc[i][j], 0, 0, 0);
        }
        __syncthreads();
    }

#pragma unroll
    for (int j = 0; j < 4; ++j) {
        int col = nBase + wc * 64 + j * 16 + lc;
        if (col < Nstore) {
            float bv = bias[col];
#pragma unroll
            for (int i = 0; i < 4; ++i) {
                int rowb = mBase + wr * 64 + i * 16 + lr * 4;
#pragma unroll
                for (int r = 0; r < 4; ++r) {
                    float v = acc[i][j][r] + bv;
                    if (RELU) v = fmaxf(v, 0.f);
                    if (OUT_BF16)
                        ((__bf16*)Cv)[(size_t)(rowb + r) * Nstore + col] = (__bf16)v;
                    else
                        ((float*)Cv)[(size_t)(rowb + r) * Nstore + col] = v;
                }
            }
        }
    }
}

// ---------------------------------------------------------------------------
// prep1: blocks [0,4096) x f32->bf16 (2048 elem/block); [4096,6144) w1
// transpose ([2048][4096] -> w1t [4096][2048]). Whole-block branch.
// ---------------------------------------------------------------------------
__global__ __launch_bounds__(256) void prep1(const float* __restrict__ x,
                                             __bf16* __restrict__ xb,
                                             const float* __restrict__ w1,
                                             __bf16* __restrict__ w1t) {
    __shared__ float tile[64 * 65];
    const int b = blockIdx.x;
    if (b < 4096) {
        int i = (b * 256 + (int)threadIdx.x) * 8;
        float4 a = *(const float4*)(x + i);
        float4 c = *(const float4*)(x + i + 4);
        bf16x8 o;
        o[0] = (__bf16)a.x; o[1] = (__bf16)a.y; o[2] = (__bf16)a.z; o[3] = (__bf16)a.w;
        o[4] = (__bf16)c.x; o[5] = (__bf16)c.y; o[6] = (__bf16)c.z; o[7] = (__bf16)c.w;
        *(bf16x8*)(xb + i) = o;
    } else {
        int l = b - 4096;                       // 32 r-tiles x 64 c-tiles
        transpose_cvt_dev(w1, w1t, IN_, HID_, l & 31, l >> 5, tile);
    }
}

// ---------------------------------------------------------------------------
// gemm1_fused: blocks [0,1024) = layer-1 GEMM (XCD-swizzled tile mapping,
// fills all CUs immediately); [1024,5120) = w2 transpose; [5120,6144) = w3
// transpose (+zero-fill rows 1000..1023). Transposes (pure-memory) overlap
// the MFMA-bound GEMM; outputs consumed only by later dispatches.
// ---------------------------------------------------------------------------
__global__ __launch_bounds__(256, 2) void gemm1_fused(const __bf16* __restrict__ xb,
                                                      const __bf16* __restrict__ w1t,
                                                      const float* __restrict__ b1,
                                                      __bf16* __restrict__ h1,
                                                      const float* __restrict__ w2,
                                                      __bf16* __restrict__ w2t,
                                                      const float* __restrict__ w3,
                                                      __bf16* __restrict__ w3t) {
    __shared__ float smem[8192];                // 32 KB, shared by both roles
    const int b = blockIdx.x;
    if (b < 1024) {
        __bf16* sA = (__bf16*)smem;
        __bf16* sB = sA + 128 * 64;
        int bx, by;
        swizzle32x32(b, bx, by);
        gemm_core<true, true>(xb, w1t, b1, h1, B_, IN_, HID_, bx, by, sA, sB);
    } else if (b < 5120) {
        int l = b - 1024;                       // 64 x 64 tiles
        transpose_cvt_dev(w2, w2t, HID_, HID_, l & 63, l >> 6, smem);
    } else {
        int l = b - 5120;                       // 64 x 16 tiles
        transpose_cvt_dev(w3, w3t, HID_, NC_, l & 63, l >> 6, smem);
    }
}

// ===========================================================================
// Layer-2 GEMM: 256x256 tile, BK=64, 8 waves (2M x 4N), uniform 4-phase
// pipeline, ZERO tile-leader / ZERO tail (R2 post-mortem fix).
// Cross-tile register prefetch:
//   - B double-buffered in regs (bqE/bqO, 8x bf16x8 each): tile t+1's B
//     frags read during P2/P3 of tile t, draining under MFMA.
//   - A m-pairs rotate through aU/aV, always read one phase ahead
//     (P3 of t reads tile t+1's m-pair0).
// Staging: ALL 4 half-tiles of tile t+2 issued in P3(t) after LGKM(12)
//   (proves every read of that LDS buffer retired -> overwrite safe).
// vmcnt gate: single VMCNT(0) per tile at P1's trailing edge, BEFORE the
//   barrier (barrier publishes all waves' DMA -> cross-wave read safe).
//   Drained loads are ~3 phases (~2400cy) old >> HBM latency -> ~free.
// Counted LGKM (ops-issued-after-needed-set): P0=4, P1=4, P2=8, P3=12.
// Same verified XOR chunk swizzle / acc mapping / epilogue as R2.
// ===========================================================================
#define PRIO1 __builtin_amdgcn_s_setprio(1)
#define PRIO0 __builtin_amdgcn_s_setprio(0)
#define BAR() __builtin_amdgcn_s_barrier()
#define LGKM(n)                                                  \
    asm volatile("s_waitcnt lgkmcnt(" #n ")" ::: "memory");      \
    __builtin_amdgcn_sched_barrier(0)
#define VMCNT(n) asm volatile("s_waitcnt vmcnt(" #n ")" ::: "memory")

// 4 ds_read_b128: A m-pair mp (rows wr*128 + (mp*2+{0,1})*16), kk=0..1.
#define RDA(dst, mp, base)                                                     \
    _Pragma("unroll") for (int mi_ = 0; mi_ < 2; ++mi_)                        \
    _Pragma("unroll") for (int kk_ = 0; kk_ < 2; ++kk_)                        \
        dst[mi_][kk_] = *(const bf16x8*)((base) +                              \
            (wr * 128 + ((mp) * 2 + mi_) * 16 + lc) * 64 +                     \
            ((kk_ * 4 + lr) ^ (lc & 7)) * 8);

// 4 ds_read_b128: B n-pair np (frags 2np, 2np+1), kk=0..1. B at base+16384.
#define RDB2(dst, np, base)                                                    \
    _Pragma("unroll") for (int j_ = 0; j_ < 2; ++j_)                           \
    _Pragma("unroll") for (int kk_ = 0; kk_ < 2; ++kk_)                        \
        dst[(np) * 2 + j_][kk_] = *(const bf16x8*)((base) + 16384 +            \
            (wc * 64 + ((np) * 2 + j_) * 16 + lc) * 64 +                       \
            ((kk_ * 4 + lr) ^ (lc & 7)) * 8);

// 16 MFMA: m-pair mp x n=0..3 x kk chain (all indices literal/static).
#define MFMA16(aset, mp, bset)                                                 \
    _Pragma("unroll") for (int mi_ = 0; mi_ < 2; ++mi_)                        \
    _Pragma("unroll") for (int n_ = 0; n_ < 4; ++n_) {                         \
        acc[(mp) * 2 + mi_][n_] = __builtin_amdgcn_mfma_f32_16x16x32_bf16(     \
            aset[mi_][0], bset[n_][0], acc[(mp) * 2 + mi_][n_], 0, 0, 0);      \
        acc[(mp) * 2 + mi_][n_] = __builtin_amdgcn_mfma_f32_16x16x32_bf16(     \
            aset[mi_][1], bset[n_][1], acc[(mp) * 2 + mi_][n_], 0, 0, 0);      \
    }

// Stage full K-tile kt (A 2 halves + B 2 halves, 8 global_load_lds/thread).
#define STAGE4(kt, base)                                                       \
    stage_half(A,  mBase,       (kt) * 64, (base));                            \
    stage_half(A,  mBase + 128, (kt) * 64, (base) + 8192);                     \
    stage_half(Bt, nBase,       (kt) * 64, (base) + 16384);                    \
    stage_half(Bt, nBase + 128, (kt) * 64, (base) + 24576);

// Steady tile: compute from CUR/bqC; prefetch tile+1 frags (NXT/bqN);
// stage tile+2 (kt2 -> CUR buffer) in P3 after LGKM(12).
#define TILE_STEADY(CUR, NXT, bqC, bqN, kt2)                                   \
    /* P0 */ RDA(aV, 1, CUR);                                                  \
    BAR(); LGKM(4); PRIO1; MFMA16(aU, 0, bqC); PRIO0; BAR();                   \
    /* P1 */ RDA(aU, 2, CUR);                                                  \
    BAR(); LGKM(4); PRIO1; MFMA16(aV, 1, bqC); PRIO0; VMCNT(0); BAR();         \
    /* P2 */ RDA(aV, 3, CUR); RDB2(bqN, 0, NXT);                               \
    BAR(); LGKM(8); PRIO1; MFMA16(aU, 2, bqC); PRIO0; BAR();                   \
    /* P3 */ RDA(aU, 0, NXT); RDB2(bqN, 1, NXT);                               \
    BAR(); LGKM(12); PRIO1; MFMA16(aV, 3, bqC); PRIO0;                         \
    STAGE4(kt2, CUR);                                                          \
    BAR();

// Drain tile (second-to-last): steady minus staging.
#define TILE_DRAIN(CUR, NXT, bqC, bqN)                                         \
    RDA(aV, 1, CUR);                                                           \
    BAR(); LGKM(4); PRIO1; MFMA16(aU, 0, bqC); PRIO0; BAR();                   \
    RDA(aU, 2, CUR);                                                           \
    BAR(); LGKM(4); PRIO1; MFMA16(aV, 1, bqC); PRIO0; VMCNT(0); BAR();         \
    RDA(aV, 3, CUR); RDB2(bqN, 0, NXT);                                        \
    BAR(); LGKM(8); PRIO1; MFMA16(aU, 2, bqC); PRIO0; BAR();                   \
    RDA(aU, 0, NXT); RDB2(bqN, 1, NXT);                                        \
    BAR(); LGKM(12); PRIO1; MFMA16(aV, 3, bqC); PRIO0; BAR();

// Last tile: no prefetch at all.
#define TILE_LAST(CUR, bqC)                                                    \
    RDA(aV, 1, CUR);                                                           \
    BAR(); LGKM(4); PRIO1; MFMA16(aU, 0, bqC); PRIO0; BAR();                   \
    RDA(aU, 2, CUR);                                                           \
    BAR(); LGKM(4); PRIO1; MFMA16(aV, 1, bqC); PRIO0; BAR();                   \
    RDA(aV, 3, CUR);                                                           \
    BAR(); LGKM(4); PRIO1; MFMA16(aU, 2, bqC); PRIO0; BAR();                   \
    LGKM(0); MFMA16(aV, 3, bqC);

__global__ __launch_bounds__(512, 2) void gemm2_256(const __bf16* __restrict__ A,
                                                    const __bf16* __restrict__ Bt,
                                                    const float* __restrict__ bias,
                                                    __bf16* __restrict__ C) {
    extern __shared__ __bf16 lds[];             // 65536 bf16 = 128 KiB
    const int tid  = threadIdx.x;
    const int lane = tid & 63;
    const int wave = tid >> 6;
    const int wr   = wave >> 2;                 // 0..1  (M)
    const int wc   = wave & 3;                  // 0..3  (N)
    const int lr   = lane >> 4;                 // 0..3
    const int lc   = lane & 15;

    // T1: XCD-aware swizzle of the 16x16 tile grid (256 blocks, %8 == 0).
    int bid = blockIdx.y * 16 + blockIdx.x;
    int xcd = bid & 7, q = bid >> 3;            // q: 0..31
    const int by = (xcd & 3) * 4 + (q & 3);     // 0..15
    const int bx = (xcd >> 2) * 8 + (q >> 2);   // 0..15
    const int mBase = by * 256;
    const int nBase = bx * 256;

    // LDS: S0 { A [0,16384) | B [16384,32768) }, S1 { +32768 }.
    __bf16* const S0p = lds;
    __bf16* const S1p = lds + 32768;

    // Stage one 128-row half (16 KB): 2 global_load_lds per thread.
    // Verified XOR chunk swizzle: slot c of row r holds global chunk c^(r&7).
    auto stage_half = [&](const __bf16* __restrict__ src, int rowBase, int k0,
                          __bf16* dst) {
#pragma unroll
        for (int it = 0; it < 2; ++it) {
            int lin = it * 512 + tid;           // 0..1023
            int rl  = lin >> 3;                 // 0..127
            int kc  = (lin & 7) ^ (rl & 7);
            const __bf16* gp = src + (size_t)(rowBase + rl) * HID_ + k0 + kc * 8;
            __builtin_amdgcn_global_load_lds(
                (__attribute__((address_space(1))) void*)gp,
                (__attribute__((address_space(3))) void*)(dst + lin * 8), 16, 0, 0);
        }
    };

    floatx4 acc[8][4];
#pragma unroll
    for (int i = 0; i < 8; ++i)
#pragma unroll
        for (int j = 0; j < 4; ++j) acc[i][j] = (floatx4)0.f;

    bf16x8 bqE[4][2], bqO[4][2];                // B frag sets (tile parity)
    bf16x8 aU[2][2], aV[2][2];                  // A m-pair rotating sets

    // Prologue: stage tiles 0 (S0) and 1 (S1); publish tile 0; prefetch
    // tile-0 frags (bqE full + aU m-pair0) exactly as a virtual P2/P3 would.
    STAGE4(0, S0p);
    STAGE4(1, S1p);
    VMCNT(8);                                   // tile-0 DMAs retired
    BAR();                                      // ...and published block-wide
    RDB2(bqE, 0, S0p);
    RDB2(bqE, 1, S0p);
    RDA(aU, 0, S0p);

    // Steady: 31 iters cover tiles 0..61; P3(60)/P3(61) stage tiles 62/63.
    for (int t = 0; t < 62; t += 2) {
        TILE_STEADY(S0p, S1p, bqE, bqO, t + 2);
        TILE_STEADY(S1p, S0p, bqO, bqE, t + 3);
    }
    TILE_DRAIN(S0p, S1p, bqE, bqO);             // tile 62
    TILE_LAST(S1p, bqO);                        // tile 63

    // Epilogue: bias + ReLU + bf16 store (h2).
#pragma unroll
    for (int n = 0; n < 4; ++n) {
        int col = nBase + wc * 64 + n * 16 + lc;
        float bv = bias[col];
#pragma unroll
        for (int m = 0; m < 8; ++m) {
            int rowb = mBase + wr * 128 + m * 16 + lr * 4;
#pragma unroll
            for (int r = 0; r < 4; ++r) {
                float v = fmaxf(acc[m][n][r] + bv, 0.f);
                C[(size_t)(rowb + r) * HID_ + col] = (__bf16)v;
            }
        }
    }
}

// ---------------------------------------------------------------------------
// Layer-3 split-K x2 (512 blocks = 2/CU): P[z][M][1024] = partial GEMM.
// ---------------------------------------------------------------------------
__global__ __launch_bounds__(256, 2) void gemm_sk(const __bf16* __restrict__ A,
                                                  const __bf16* __restrict__ Bt,
                                                  float* __restrict__ P,
                                                  int M, int KH, int Ktot) {
    __shared__ __bf16 sA[128 * 64];
    __shared__ __bf16 sB[128 * 64];

    const int tid   = threadIdx.x;
    const int lane  = tid & 63;
    const int wave  = tid >> 6;
    const int wr    = wave >> 1;
    const int wc    = wave & 1;
    const int mBase = blockIdx.y * 128;
    const int nBase = blockIdx.x * 128;
    const int z     = blockIdx.z;
    const int kOff  = z * KH;
    const int lr    = lane >> 4;
    const int lc    = lane & 15;

    floatx4 acc[4][4];
#pragma unroll
    for (int i = 0; i < 4; ++i)
#pragma unroll
        for (int j = 0; j < 4; ++j) acc[i][j] = (floatx4)0.f;

    for (int k0 = kOff; k0 < kOff + KH; k0 += 64) {
#pragma unroll
        for (int it = 0; it < 4; ++it) {
            int lin = it * 256 + tid;
            int r   = lin >> 3;
            int kc  = (lin & 7) ^ (r & 7);
            const __bf16* ga = A  + (size_t)(mBase + r) * Ktot + k0 + kc * 8;
            const __bf16* gb = Bt + (size_t)(nBase + r) * Ktot + k0 + kc * 8;
            __builtin_amdgcn_global_load_lds(
                (__attribute__((address_space(1))) void*)ga,
                (__attribute__((address_space(3))) void*)(sA + lin * 8), 16, 0, 0);
            __builtin_amdgcn_global_load_lds(
                (__attribute__((address_space(1))) void*)gb,
                (__attribute__((address_space(3))) void*)(sB + lin * 8), 16, 0, 0);
        }
        __builtin_amdgcn_s_waitcnt(0);
        __syncthreads();

#pragma unroll
        for (int kk = 0; kk < 2; ++kk) {
            const int sw = (kk * 4 + lr) ^ (lc & 7);
            bf16x8 af[4], bfr[4];
#pragma unroll
            for (int i = 0; i < 4; ++i)
                af[i] = *(const bf16x8*)(sA + (wr * 64 + i * 16 + lc) * 64 + sw * 8);
#pragma unroll
            for (int j = 0; j < 4; ++j)
                bfr[j] = *(const bf16x8*)(sB + (wc * 64 + j * 16 + lc) * 64 + sw * 8);
#pragma unroll
            for (int i = 0; i < 4; ++i)
#pragma unroll
                for (int j = 0; j < 4; ++j)
                    acc[i][j] = __builtin_amdgcn_mfma_f32_16x16x32_bf16(af[i], bfr[j], acc[i][j], 0, 0, 0);
        }
        __syncthreads();
    }

    float* Pz = P + (size_t)z * M * NCP_;
#pragma unroll
    for (int j = 0; j < 4; ++j) {
        int col = nBase + wc * 64 + j * 16 + lc;
#pragma unroll
        for (int i = 0; i < 4; ++i) {
            int rowb = mBase + wr * 64 + i * 16 + lr * 4;
#pragma unroll
            for (int r = 0; r < 4; ++r)
                Pz[(size_t)(rowb + r) * NCP_ + col] = acc[i][j][r];
        }
    }
}

// ---------------------------------------------------------------------------
// out[m][c] = P0[m][c] + P1[m][c] + b3[c], c < 1000. grid (4, 4096).
// ---------------------------------------------------------------------------
__global__ __launch_bounds__(256) void reduce_bias(const float* __restrict__ P,
                                                   const float* __restrict__ b3,
                                                   float* __restrict__ out) {
    int c = blockIdx.x * 256 + threadIdx.x;
    int m = blockIdx.y;
    if (c < NC_)
        out[(size_t)m * NC_ + c] =
            P[(size_t)m * NCP_ + c] + P[(size_t)(B_ + m) * NCP_ + c] + b3[c];
}

extern "C" void kernel_launch(void* const* d_in, const int* in_sizes, int n_in,
                              void* d_out, int out_size, void* d_ws, size_t ws_size,
                              hipStream_t stream) {
    const float* x  = (const float*)d_in[0];
    const float* w1 = (const float*)d_in[1];
    const float* b1 = (const float*)d_in[2];
    const float* w2 = (const float*)d_in[3];
    const float* b2 = (const float*)d_in[4];
    const float* w3 = (const float*)d_in[5];
    const float* b3 = (const float*)d_in[6];
    float* out = (float*)d_out;

    // ws (MiB): [0,16) xb | [16,32) w1t | [32,64) w2t | [64,72) w3t |
    // [72,104) h1. h2 aliases [0,32) (xb/w1t dead after gemm1);
    // split-K partials P alias [72,104) (h1 dead after gemm2). 104 MiB.
    char* ws = (char*)d_ws;
    __bf16* xb  = (__bf16*)(ws);
    __bf16* w1t = (__bf16*)(ws + (16u << 20));
    __bf16* w2t = (__bf16*)(ws + (32u << 20));
    __bf16* w3t = (__bf16*)(ws + (64u << 20));
    __bf16* h1  = (__bf16*)(ws + (72u << 20));
    __bf16* h2  = (__bf16*)(ws);
    float*  P   = (float*)(ws + (72u << 20));

    // 128 KiB dynamic LDS for gemm2_256.
    static int attr_done = 0;
    if (!attr_done) {
        (void)hipFuncSetAttribute((const void*)gemm2_256,
                                  hipFuncAttributeMaxDynamicSharedMemorySize,
                                  131072);
        attr_done = 1;
    }

    prep1<<<6144, 256, 0, stream>>>(x, xb, w1, w1t);

    gemm1_fused<<<6144, 256, 0, stream>>>(xb, w1t, b1, h1, w2, w2t, w3, w3t);

    gemm2_256<<<dim3(16, 16), 512, 131072, stream>>>(h1, w2t, b2, h2);

    gemm_sk<<<dim3(NCP_ / 128, B_ / 128, 2), 256, 0, stream>>>(
        h2, w3t, P, B_, HID_ / 2, HID_);
    reduce_bias<<<dim3(NCP_ / 256, B_), 256, 0, stream>>>(P, b3, out);
}

// Round 4
// 621.857 us; speedup vs baseline: 1.0277x; 1.0277x over previous
//
#include <hip/hip_runtime.h>
#include <hip/hip_bf16.h>

typedef __bf16 bf16x8 __attribute__((ext_vector_type(8)));
typedef __bf16 bf16x4 __attribute__((ext_vector_type(4)));
typedef float floatx4 __attribute__((ext_vector_type(4)));

#define B_    4096
#define IN_   2048
#define HID_  4096
#define NC_   1000
#define NCP_  1024

// ---------------------------------------------------------------------------
// Transpose+convert device body: src [R][C] f32 -> dst [c][r] bf16, c range
// [64*by, 64*by+63] (c >= C zero-filled; dst padded). Stride-65 f32 tile:
// phase-1 writes conflict-free, phase-2 reads 2-way (free). 16B stores.
// ---------------------------------------------------------------------------
__device__ __forceinline__ void transpose_cvt_dev(const float* __restrict__ src,
                                                  __bf16* __restrict__ dst,
                                                  int R, int C, int bx, int by,
                                                  float* tile /* >= 64*65 f32 */) {
    const int r0 = bx * 64;
    const int c0 = by * 64;
    const int t  = threadIdx.x;
#pragma unroll
    for (int it = 0; it < 4; ++it) {
        int lin = it * 256 + t;
        int sr = lin >> 4, c4 = lin & 15;
        int cb = c0 + c4 * 4;
        const float* s = src + (size_t)(r0 + sr) * C;
        float4 v;
        if (cb + 3 < C) {
            v = *(const float4*)(s + cb);
        } else {
            v.x = (cb + 0 < C) ? s[cb + 0] : 0.f;
            v.y = (cb + 1 < C) ? s[cb + 1] : 0.f;
            v.z = (cb + 2 < C) ? s[cb + 2] : 0.f;
            v.w = (cb + 3 < C) ? s[cb + 3] : 0.f;
        }
        tile[(c4 * 4 + 0) * 65 + sr] = v.x;
        tile[(c4 * 4 + 1) * 65 + sr] = v.y;
        tile[(c4 * 4 + 2) * 65 + sr] = v.z;
        tile[(c4 * 4 + 3) * 65 + sr] = v.w;
    }
    __syncthreads();
#pragma unroll
    for (int it = 0; it < 2; ++it) {
        int lin = it * 256 + t;                 // 0..511
        int dr = lin >> 3, q8 = lin & 7;
        bf16x8 o;
#pragma unroll
        for (int j = 0; j < 8; ++j) o[j] = (__bf16)tile[dr * 65 + q8 * 8 + j];
        *(bf16x8*)(dst + (size_t)(c0 + dr) * R + r0 + q8 * 8) = o;
    }
}

// ---------------------------------------------------------------------------
// XCD-aware swizzle for a 32x32 tile grid (gemm1 / 128x128 core).
// ---------------------------------------------------------------------------
__device__ __forceinline__ void swizzle32x32(int bid, int& bx, int& by) {
    int xcd = bid & 7;
    int q   = bid >> 3;                         // 0..127
    by = ((xcd >> 2) << 4) + (q & 15);          // patch row: 2 x 16
    bx = ((xcd & 3) << 3) + (q >> 4);           // patch col: 4 x 8
}

// ---------------------------------------------------------------------------
// GEMM core (R2-verified, DO NOT PERTURB): 128x128 block, 4 waves (2x2),
// wave 64x64 as 4x4 MFMA 16x16x32 frags. XOR swizzle: LDS slot (r,c) holds
// global chunk c^(r&7); frag reads use chunk (kk*4+lr)^(lc&7) ->
// SQ_LDS_BANK_CONFLICT == 0 (measured R2/R4/R5/R6/R7, 1074 TF).
// Used by gemm1_fused and gemm_sk. Layer-2 uses gemm2_256 below.
// ---------------------------------------------------------------------------
template <bool RELU, bool OUT_BF16>
__device__ __forceinline__ void gemm_core(const __bf16* __restrict__ A,
                                          const __bf16* __restrict__ Bt,
                                          const float* __restrict__ bias,
                                          void* __restrict__ Cv,
                                          int M, int K, int Nstore,
                                          int bx, int by,
                                          __bf16* sA, __bf16* sB) {
    const int tid   = threadIdx.x;
    const int lane  = tid & 63;
    const int wave  = tid >> 6;
    const int wr    = wave >> 1;
    const int wc    = wave & 1;
    const int mBase = by * 128;
    const int nBase = bx * 128;
    const int lr    = lane >> 4;
    const int lc    = lane & 15;

    floatx4 acc[4][4];
#pragma unroll
    for (int i = 0; i < 4; ++i)
#pragma unroll
        for (int j = 0; j < 4; ++j) acc[i][j] = (floatx4)0.f;

    for (int k0 = 0; k0 < K; k0 += 64) {
#pragma unroll
        for (int it = 0; it < 4; ++it) {
            int lin = it * 256 + tid;
            int r   = lin >> 3;
            int kc  = (lin & 7) ^ (r & 7);          // XOR swizzle
            const __bf16* ga = A  + (size_t)(mBase + r) * K + k0 + kc * 8;
            const __bf16* gb = Bt + (size_t)(nBase + r) * K + k0 + kc * 8;
            __builtin_amdgcn_global_load_lds(
                (__attribute__((address_space(1))) void*)ga,
                (__attribute__((address_space(3))) void*)(sA + lin * 8), 16, 0, 0);
            __builtin_amdgcn_global_load_lds(
                (__attribute__((address_space(1))) void*)gb,
                (__attribute__((address_space(3))) void*)(sB + lin * 8), 16, 0, 0);
        }
        __builtin_amdgcn_s_waitcnt(0);
        __syncthreads();

#pragma unroll
        for (int kk = 0; kk < 2; ++kk) {
            const int sw = (kk * 4 + lr) ^ (lc & 7);   // swizzled chunk
            bf16x8 af[4], bfr[4];
#pragma unroll
            for (int i = 0; i < 4; ++i)
                af[i] = *(const bf16x8*)(sA + (wr * 64 + i * 16 + lc) * 64 + sw * 8);
#pragma unroll
            for (int j = 0; j < 4; ++j)
                bfr[j] = *(const bf16x8*)(sB + (wc * 64 + j * 16 + lc) * 64 + sw * 8);
#pragma unroll
            for (int i = 0; i < 4; ++i)
#pragma unroll
                for (int j = 0; j < 4; ++j)
                    acc[i][j] = __builtin_amdgcn_mfma_f32_16x16x32_bf16(af[i], bfr[j], acc[i][j], 0, 0, 0);
        }
        __syncthreads();
    }

#pragma unroll
    for (int j = 0; j < 4; ++j) {
        int col = nBase + wc * 64 + j * 16 + lc;
        if (col < Nstore) {
            float bv = bias[col];
#pragma unroll
            for (int i = 0; i < 4; ++i) {
                int rowb = mBase + wr * 64 + i * 16 + lr * 4;
#pragma unroll
                for (int r = 0; r < 4; ++r) {
                    float v = acc[i][j][r] + bv;
                    if (RELU) v = fmaxf(v, 0.f);
                    if (OUT_BF16)
                        ((__bf16*)Cv)[(size_t)(rowb + r) * Nstore + col] = (__bf16)v;
                    else
                        ((float*)Cv)[(size_t)(rowb + r) * Nstore + col] = v;
                }
            }
        }
    }
}

// ---------------------------------------------------------------------------
// prep1: blocks [0,4096) x f32->bf16 (2048 elem/block); [4096,6144) w1
// transpose ([2048][4096] -> w1t [4096][2048]). Whole-block branch.
// ---------------------------------------------------------------------------
__global__ __launch_bounds__(256) void prep1(const float* __restrict__ x,
                                             __bf16* __restrict__ xb,
                                             const float* __restrict__ w1,
                                             __bf16* __restrict__ w1t) {
    __shared__ float tile[64 * 65];
    const int b = blockIdx.x;
    if (b < 4096) {
        int i = (b * 256 + (int)threadIdx.x) * 8;
        float4 a = *(const float4*)(x + i);
        float4 c = *(const float4*)(x + i + 4);
        bf16x8 o;
        o[0] = (__bf16)a.x; o[1] = (__bf16)a.y; o[2] = (__bf16)a.z; o[3] = (__bf16)a.w;
        o[4] = (__bf16)c.x; o[5] = (__bf16)c.y; o[6] = (__bf16)c.z; o[7] = (__bf16)c.w;
        *(bf16x8*)(xb + i) = o;
    } else {
        int l = b - 4096;                       // 32 r-tiles x 64 c-tiles
        transpose_cvt_dev(w1, w1t, IN_, HID_, l & 31, l >> 5, tile);
    }
}

// ---------------------------------------------------------------------------
// gemm1_fused: blocks [0,1024) = layer-1 GEMM (XCD-swizzled tile mapping,
// fills all CUs immediately); [1024,5120) = w2 transpose; [5120,6144) = w3
// transpose (+zero-fill rows 1000..1023). Transposes (pure-memory) overlap
// the MFMA-bound GEMM; outputs consumed only by later dispatches.
// ---------------------------------------------------------------------------
__global__ __launch_bounds__(256, 2) void gemm1_fused(const __bf16* __restrict__ xb,
                                                      const __bf16* __restrict__ w1t,
                                                      const float* __restrict__ b1,
                                                      __bf16* __restrict__ h1,
                                                      const float* __restrict__ w2,
                                                      __bf16* __restrict__ w2t,
                                                      const float* __restrict__ w3,
                                                      __bf16* __restrict__ w3t) {
    __shared__ float smem[8192];                // 32 KB, shared by both roles
    const int b = blockIdx.x;
    if (b < 1024) {
        __bf16* sA = (__bf16*)smem;
        __bf16* sB = sA + 128 * 64;
        int bx, by;
        swizzle32x32(b, bx, by);
        gemm_core<true, true>(xb, w1t, b1, h1, B_, IN_, HID_, bx, by, sA, sB);
    } else if (b < 5120) {
        int l = b - 1024;                       // 64 x 64 tiles
        transpose_cvt_dev(w2, w2t, HID_, HID_, l & 63, l >> 6, smem);
    } else {
        int l = b - 5120;                       // 64 x 16 tiles
        transpose_cvt_dev(w3, w3t, HID_, NC_, l & 63, l >> 6, smem);
    }
}

// ===========================================================================
// Layer-2 GEMM: 256x256 tile, BK=64, 8 waves (2M x 4N), uniform 4-phase
// pipeline, zero tile-leader / zero tail (R3 structure, unchanged).
// R3 POST-MORTEM FIX (R4): __launch_bounds__(512, 1), NOT (512, 2).
//   (512,2) pinned 4 waves/SIMD -> hard 128-VGPR cap; demand is ~250 ->
//   ~120 regs spilled to scratch (measured: FETCH +145 MB, WRITE +23 MB,
//   VALUBusy 7.6%, MfmaUtil 16%). (512,1) relaxes to 2 waves/SIMD ->
//   256-VGPR cap; 8-wave block still fully occupies the CU (1 block/CU,
//   grid = 256 = #CUs). Pipelining replaces TLP, as in the m201 template.
// Cross-tile register prefetch:
//   - B double-buffered in regs (bqE/bqO): tile t+1's B frags read during
//     P2/P3 of tile t, draining under MFMA.
//   - A m-pairs rotate through aU/aV, always read one phase ahead.
// Staging: ALL 4 half-tiles of tile t+2 issued in P3(t) after LGKM(12)
//   (proves every read of that LDS buffer retired -> overwrite safe).
// vmcnt gate: single VMCNT(0) per tile at P1's trailing edge, BEFORE the
//   barrier (barrier publishes all waves' DMA -> cross-wave read safe).
// Counted LGKM (ops-issued-after-needed-set): P0=4, P1=4, P2=8, P3=12.
// Same verified XOR chunk swizzle / acc mapping / epilogue as R2/R3.
// ===========================================================================
#define PRIO1 __builtin_amdgcn_s_setprio(1)
#define PRIO0 __builtin_amdgcn_s_setprio(0)
#define BAR() __builtin_amdgcn_s_barrier()
#define LGKM(n)                                                  \
    asm volatile("s_waitcnt lgkmcnt(" #n ")" ::: "memory");      \
    __builtin_amdgcn_sched_barrier(0)
#define VMCNT(n) asm volatile("s_waitcnt vmcnt(" #n ")" ::: "memory")

// 4 ds_read_b128: A m-pair mp (rows wr*128 + (mp*2+{0,1})*16), kk=0..1.
#define RDA(dst, mp, base)                                                     \
    _Pragma("unroll") for (int mi_ = 0; mi_ < 2; ++mi_)                        \
    _Pragma("unroll") for (int kk_ = 0; kk_ < 2; ++kk_)                        \
        dst[mi_][kk_] = *(const bf16x8*)((base) +                              \
            (wr * 128 + ((mp) * 2 + mi_) * 16 + lc) * 64 +                     \
            ((kk_ * 4 + lr) ^ (lc & 7)) * 8);

// 4 ds_read_b128: B n-pair np (frags 2np, 2np+1), kk=0..1. B at base+16384.
#define RDB2(dst, np, base)                                                    \
    _Pragma("unroll") for (int j_ = 0; j_ < 2; ++j_)                           \
    _Pragma("unroll") for (int kk_ = 0; kk_ < 2; ++kk_)                        \
        dst[(np) * 2 + j_][kk_] = *(const bf16x8*)((base) + 16384 +            \
            (wc * 64 + ((np) * 2 + j_) * 16 + lc) * 64 +                       \
            ((kk_ * 4 + lr) ^ (lc & 7)) * 8);

// 16 MFMA: m-pair mp x n=0..3 x kk chain (all indices literal/static).
#define MFMA16(aset, mp, bset)                                                 \
    _Pragma("unroll") for (int mi_ = 0; mi_ < 2; ++mi_)                        \
    _Pragma("unroll") for (int n_ = 0; n_ < 4; ++n_) {                         \
        acc[(mp) * 2 + mi_][n_] = __builtin_amdgcn_mfma_f32_16x16x32_bf16(     \
            aset[mi_][0], bset[n_][0], acc[(mp) * 2 + mi_][n_], 0, 0, 0);      \
        acc[(mp) * 2 + mi_][n_] = __builtin_amdgcn_mfma_f32_16x16x32_bf16(     \
            aset[mi_][1], bset[n_][1], acc[(mp) * 2 + mi_][n_], 0, 0, 0);      \
    }

// Stage full K-tile kt (A 2 halves + B 2 halves, 8 global_load_lds/thread).
#define STAGE4(kt, base)                                                       \
    stage_half(A,  mBase,       (kt) * 64, (base));                            \
    stage_half(A,  mBase + 128, (kt) * 64, (base) + 8192);                     \
    stage_half(Bt, nBase,       (kt) * 64, (base) + 16384);                    \
    stage_half(Bt, nBase + 128, (kt) * 64, (base) + 24576);

// Steady tile: compute from CUR/bqC; prefetch tile+1 frags (NXT/bqN);
// stage tile+2 (kt2 -> CUR buffer) in P3 after LGKM(12).
#define TILE_STEADY(CUR, NXT, bqC, bqN, kt2)                                   \
    /* P0 */ RDA(aV, 1, CUR);                                                  \
    BAR(); LGKM(4); PRIO1; MFMA16(aU, 0, bqC); PRIO0; BAR();                   \
    /* P1 */ RDA(aU, 2, CUR);                                                  \
    BAR(); LGKM(4); PRIO1; MFMA16(aV, 1, bqC); PRIO0; VMCNT(0); BAR();         \
    /* P2 */ RDA(aV, 3, CUR); RDB2(bqN, 0, NXT);                               \
    BAR(); LGKM(8); PRIO1; MFMA16(aU, 2, bqC); PRIO0; BAR();                   \
    /* P3 */ RDA(aU, 0, NXT); RDB2(bqN, 1, NXT);                               \
    BAR(); LGKM(12); PRIO1; MFMA16(aV, 3, bqC); PRIO0;                         \
    STAGE4(kt2, CUR);                                                          \
    BAR();

// Drain tile (second-to-last): steady minus staging.
#define TILE_DRAIN(CUR, NXT, bqC, bqN)                                         \
    RDA(aV, 1, CUR);                                                           \
    BAR(); LGKM(4); PRIO1; MFMA16(aU, 0, bqC); PRIO0; BAR();                   \
    RDA(aU, 2, CUR);                                                           \
    BAR(); LGKM(4); PRIO1; MFMA16(aV, 1, bqC); PRIO0; VMCNT(0); BAR();         \
    RDA(aV, 3, CUR); RDB2(bqN, 0, NXT);                                        \
    BAR(); LGKM(8); PRIO1; MFMA16(aU, 2, bqC); PRIO0; BAR();                   \
    RDA(aU, 0, NXT); RDB2(bqN, 1, NXT);                                        \
    BAR(); LGKM(12); PRIO1; MFMA16(aV, 3, bqC); PRIO0; BAR();

// Last tile: no prefetch at all.
#define TILE_LAST(CUR, bqC)                                                    \
    RDA(aV, 1, CUR);                                                           \
    BAR(); LGKM(4); PRIO1; MFMA16(aU, 0, bqC); PRIO0; BAR();                   \
    RDA(aU, 2, CUR);                                                           \
    BAR(); LGKM(4); PRIO1; MFMA16(aV, 1, bqC); PRIO0; BAR();                   \
    RDA(aV, 3, CUR);                                                           \
    BAR(); LGKM(4); PRIO1; MFMA16(aU, 2, bqC); PRIO0; BAR();                   \
    LGKM(0); MFMA16(aV, 3, bqC);

__global__ __launch_bounds__(512, 1) void gemm2_256(const __bf16* __restrict__ A,
                                                    const __bf16* __restrict__ Bt,
                                                    const float* __restrict__ bias,
                                                    __bf16* __restrict__ C) {
    extern __shared__ __bf16 lds[];             // 65536 bf16 = 128 KiB
    const int tid  = threadIdx.x;
    const int lane = tid & 63;
    const int wave = tid >> 6;
    const int wr   = wave >> 2;                 // 0..1  (M)
    const int wc   = wave & 3;                  // 0..3  (N)
    const int lr   = lane >> 4;                 // 0..3
    const int lc   = lane & 15;

    // T1: XCD-aware swizzle of the 16x16 tile grid (256 blocks, %8 == 0).
    int bid = blockIdx.y * 16 + blockIdx.x;
    int xcd = bid & 7, q = bid >> 3;            // q: 0..31
    const int by = (xcd & 3) * 4 + (q & 3);     // 0..15
    const int bx = (xcd >> 2) * 8 + (q >> 2);   // 0..15
    const int mBase = by * 256;
    const int nBase = bx * 256;

    // LDS: S0 { A [0,16384) | B [16384,32768) }, S1 { +32768 }.
    __bf16* const S0p = lds;
    __bf16* const S1p = lds + 32768;

    // Stage one 128-row half (16 KB): 2 global_load_lds per thread.
    // Verified XOR chunk swizzle: slot c of row r holds global chunk c^(r&7).
    auto stage_half = [&](const __bf16* __restrict__ src, int rowBase, int k0,
                          __bf16* dst) {
#pragma unroll
        for (int it = 0; it < 2; ++it) {
            int lin = it * 512 + tid;           // 0..1023
            int rl  = lin >> 3;                 // 0..127
            int kc  = (lin & 7) ^ (rl & 7);
            const __bf16* gp = src + (size_t)(rowBase + rl) * HID_ + k0 + kc * 8;
            __builtin_amdgcn_global_load_lds(
                (__attribute__((address_space(1))) void*)gp,
                (__attribute__((address_space(3))) void*)(dst + lin * 8), 16, 0, 0);
        }
    };

    floatx4 acc[8][4];
#pragma unroll
    for (int i = 0; i < 8; ++i)
#pragma unroll
        for (int j = 0; j < 4; ++j) acc[i][j] = (floatx4)0.f;

    bf16x8 bqE[4][2], bqO[4][2];                // B frag sets (tile parity)
    bf16x8 aU[2][2], aV[2][2];                  // A m-pair rotating sets

    // Prologue: stage tiles 0 (S0) and 1 (S1); publish tile 0; prefetch
    // tile-0 frags (bqE full + aU m-pair0) exactly as a virtual P2/P3 would.
    STAGE4(0, S0p);
    STAGE4(1, S1p);
    VMCNT(8);                                   // tile-0 DMAs retired
    BAR();                                      // ...and published block-wide
    RDB2(bqE, 0, S0p);
    RDB2(bqE, 1, S0p);
    RDA(aU, 0, S0p);

    // Steady: 31 iters cover tiles 0..61; P3(60)/P3(61) stage tiles 62/63.
    for (int t = 0; t < 62; t += 2) {
        TILE_STEADY(S0p, S1p, bqE, bqO, t + 2);
        TILE_STEADY(S1p, S0p, bqO, bqE, t + 3);
    }
    TILE_DRAIN(S0p, S1p, bqE, bqO);             // tile 62
    TILE_LAST(S1p, bqO);                        // tile 63

    // Epilogue: bias + ReLU + bf16 store (h2).
#pragma unroll
    for (int n = 0; n < 4; ++n) {
        int col = nBase + wc * 64 + n * 16 + lc;
        float bv = bias[col];
#pragma unroll
        for (int m = 0; m < 8; ++m) {
            int rowb = mBase + wr * 128 + m * 16 + lr * 4;
#pragma unroll
            for (int r = 0; r < 4; ++r) {
                float v = fmaxf(acc[m][n][r] + bv, 0.f);
                C[(size_t)(rowb + r) * HID_ + col] = (__bf16)v;
            }
        }
    }
}

// ---------------------------------------------------------------------------
// Layer-3 split-K x2 (512 blocks = 2/CU): P[z][M][1024] = partial GEMM.
// ---------------------------------------------------------------------------
__global__ __launch_bounds__(256, 2) void gemm_sk(const __bf16* __restrict__ A,
                                                  const __bf16* __restrict__ Bt,
                                                  float* __restrict__ P,
                                                  int M, int KH, int Ktot) {
    __shared__ __bf16 sA[128 * 64];
    __shared__ __bf16 sB[128 * 64];

    const int tid   = threadIdx.x;
    const int lane  = tid & 63;
    const int wave  = tid >> 6;
    const int wr    = wave >> 1;
    const int wc    = wave & 1;
    const int mBase = blockIdx.y * 128;
    const int nBase = blockIdx.x * 128;
    const int z     = blockIdx.z;
    const int kOff  = z * KH;
    const int lr    = lane >> 4;
    const int lc    = lane & 15;

    floatx4 acc[4][4];
#pragma unroll
    for (int i = 0; i < 4; ++i)
#pragma unroll
        for (int j = 0; j < 4; ++j) acc[i][j] = (floatx4)0.f;

    for (int k0 = kOff; k0 < kOff + KH; k0 += 64) {
#pragma unroll
        for (int it = 0; it < 4; ++it) {
            int lin = it * 256 + tid;
            int r   = lin >> 3;
            int kc  = (lin & 7) ^ (r & 7);
            const __bf16* ga = A  + (size_t)(mBase + r) * Ktot + k0 + kc * 8;
            const __bf16* gb = Bt + (size_t)(nBase + r) * Ktot + k0 + kc * 8;
            __builtin_amdgcn_global_load_lds(
                (__attribute__((address_space(1))) void*)ga,
                (__attribute__((address_space(3))) void*)(sA + lin * 8), 16, 0, 0);
            __builtin_amdgcn_global_load_lds(
                (__attribute__((address_space(1))) void*)gb,
                (__attribute__((address_space(3))) void*)(sB + lin * 8), 16, 0, 0);
        }
        __builtin_amdgcn_s_waitcnt(0);
        __syncthreads();

#pragma unroll
        for (int kk = 0; kk < 2; ++kk) {
            const int sw = (kk * 4 + lr) ^ (lc & 7);
            bf16x8 af[4], bfr[4];
#pragma unroll
            for (int i = 0; i < 4; ++i)
                af[i] = *(const bf16x8*)(sA + (wr * 64 + i * 16 + lc) * 64 + sw * 8);
#pragma unroll
            for (int j = 0; j < 4; ++j)
                bfr[j] = *(const bf16x8*)(sB + (wc * 64 + j * 16 + lc) * 64 + sw * 8);
#pragma unroll
            for (int i = 0; i < 4; ++i)
#pragma unroll
                for (int j = 0; j < 4; ++j)
                    acc[i][j] = __builtin_amdgcn_mfma_f32_16x16x32_bf16(af[i], bfr[j], acc[i][j], 0, 0, 0);
        }
        __syncthreads();
    }

    float* Pz = P + (size_t)z * M * NCP_;
#pragma unroll
    for (int j = 0; j < 4; ++j) {
        int col = nBase + wc * 64 + j * 16 + lc;
#pragma unroll
        for (int i = 0; i < 4; ++i) {
            int rowb = mBase + wr * 64 + i * 16 + lr * 4;
#pragma unroll
            for (int r = 0; r < 4; ++r)
                Pz[(size_t)(rowb + r) * NCP_ + col] = acc[i][j][r];
        }
    }
}

// ---------------------------------------------------------------------------
// out[m][c] = P0[m][c] + P1[m][c] + b3[c], c < 1000. grid (4, 4096).
// ---------------------------------------------------------------------------
__global__ __launch_bounds__(256) void reduce_bias(const float* __restrict__ P,
                                                   const float* __restrict__ b3,
                                                   float* __restrict__ out) {
    int c = blockIdx.x * 256 + threadIdx.x;
    int m = blockIdx.y;
    if (c < NC_)
        out[(size_t)m * NC_ + c] =
            P[(size_t)m * NCP_ + c] + P[(size_t)(B_ + m) * NCP_ + c] + b3[c];
}

extern "C" void kernel_launch(void* const* d_in, const int* in_sizes, int n_in,
                              void* d_out, int out_size, void* d_ws, size_t ws_size,
                              hipStream_t stream) {
    const float* x  = (const float*)d_in[0];
    const float* w1 = (const float*)d_in[1];
    const float* b1 = (const float*)d_in[2];
    const float* w2 = (const float*)d_in[3];
    const float* b2 = (const float*)d_in[4];
    const float* w3 = (const float*)d_in[5];
    const float* b3 = (const float*)d_in[6];
    float* out = (float*)d_out;

    // ws (MiB): [0,16) xb | [16,32) w1t | [32,64) w2t | [64,72) w3t |
    // [72,104) h1. h2 aliases [0,32) (xb/w1t dead after gemm1);
    // split-K partials P alias [72,104) (h1 dead after gemm2). 104 MiB.
    char* ws = (char*)d_ws;
    __bf16* xb  = (__bf16*)(ws);
    __bf16* w1t = (__bf16*)(ws + (16u << 20));
    __bf16* w2t = (__bf16*)(ws + (32u << 20));
    __bf16* w3t = (__bf16*)(ws + (64u << 20));
    __bf16* h1  = (__bf16*)(ws + (72u << 20));
    __bf16* h2  = (__bf16*)(ws);
    float*  P   = (float*)(ws + (72u << 20));

    // 128 KiB dynamic LDS for gemm2_256.
    static int attr_done = 0;
    if (!attr_done) {
        (void)hipFuncSetAttribute((const void*)gemm2_256,
                                  hipFuncAttributeMaxDynamicSharedMemorySize,
                                  131072);
        attr_done = 1;
    }

    prep1<<<6144, 256, 0, stream>>>(x, xb, w1, w1t);

    gemm1_fused<<<6144, 256, 0, stream>>>(xb, w1t, b1, h1, w2, w2t, w3, w3t);

    gemm2_256<<<dim3(16, 16), 512, 131072, stream>>>(h1, w2t, b2, h2);

    gemm_sk<<<dim3(NCP_ / 128, B_ / 128, 2), 256, 0, stream>>>(
        h2, w3t, P, B_, HID_ / 2, HID_);
    reduce_bias<<<dim3(NCP_ / 256, B_), 256, 0, stream>>>(P, b3, out);
}

// Round 5
// 424.655 us; speedup vs baseline: 1.5049x; 1.4644x over previous
//
#include <hip/hip_runtime.h>
#include <hip/hip_bf16.h>

typedef __bf16 bf16x8 __attribute__((ext_vector_type(8)));
typedef __bf16 bf16x4 __attribute__((ext_vector_type(4)));
typedef float floatx4 __attribute__((ext_vector_type(4)));

#define B_    4096
#define IN_   2048
#define HID_  4096
#define NC_   1000
#define NCP_  1024

// ---------------------------------------------------------------------------
// Transpose+convert device body: src [R][C] f32 -> dst [c][r] bf16, c range
// [64*by, 64*by+63] (c >= C zero-filled; dst padded). Stride-65 f32 tile:
// phase-1 writes conflict-free, phase-2 reads 2-way (free). 16B stores.
// ---------------------------------------------------------------------------
__device__ __forceinline__ void transpose_cvt_dev(const float* __restrict__ src,
                                                  __bf16* __restrict__ dst,
                                                  int R, int C, int bx, int by,
                                                  float* tile /* >= 64*65 f32 */) {
    const int r0 = bx * 64;
    const int c0 = by * 64;
    const int t  = threadIdx.x;
#pragma unroll
    for (int it = 0; it < 4; ++it) {
        int lin = it * 256 + t;
        int sr = lin >> 4, c4 = lin & 15;
        int cb = c0 + c4 * 4;
        const float* s = src + (size_t)(r0 + sr) * C;
        float4 v;
        if (cb + 3 < C) {
            v = *(const float4*)(s + cb);
        } else {
            v.x = (cb + 0 < C) ? s[cb + 0] : 0.f;
            v.y = (cb + 1 < C) ? s[cb + 1] : 0.f;
            v.z = (cb + 2 < C) ? s[cb + 2] : 0.f;
            v.w = (cb + 3 < C) ? s[cb + 3] : 0.f;
        }
        tile[(c4 * 4 + 0) * 65 + sr] = v.x;
        tile[(c4 * 4 + 1) * 65 + sr] = v.y;
        tile[(c4 * 4 + 2) * 65 + sr] = v.z;
        tile[(c4 * 4 + 3) * 65 + sr] = v.w;
    }
    __syncthreads();
#pragma unroll
    for (int it = 0; it < 2; ++it) {
        int lin = it * 256 + t;                 // 0..511
        int dr = lin >> 3, q8 = lin & 7;
        bf16x8 o;
#pragma unroll
        for (int j = 0; j < 8; ++j) o[j] = (__bf16)tile[dr * 65 + q8 * 8 + j];
        *(bf16x8*)(dst + (size_t)(c0 + dr) * R + r0 + q8 * 8) = o;
    }
}

// ---------------------------------------------------------------------------
// XCD-aware swizzle for a 32x32 tile grid (gemm1 / 128x128 core).
// ---------------------------------------------------------------------------
__device__ __forceinline__ void swizzle32x32(int bid, int& bx, int& by) {
    int xcd = bid & 7;
    int q   = bid >> 3;                         // 0..127
    by = ((xcd >> 2) << 4) + (q & 15);          // patch row: 2 x 16
    bx = ((xcd & 3) << 3) + (q >> 4);           // patch col: 4 x 8
}

// ---------------------------------------------------------------------------
// GEMM core (R2-verified, DO NOT PERTURB): 128x128 block, 4 waves (2x2),
// wave 64x64 as 4x4 MFMA 16x16x32 frags. XOR swizzle: LDS slot (r,c) holds
// global chunk c^(r&7); frag reads use chunk (kk*4+lr)^(lc&7) ->
// SQ_LDS_BANK_CONFLICT == 0 (measured, 1074 TF).
// Used by gemm1_fused and gemm_sk. Layer-2 uses gemm2_256 below.
// ---------------------------------------------------------------------------
template <bool RELU, bool OUT_BF16>
__device__ __forceinline__ void gemm_core(const __bf16* __restrict__ A,
                                          const __bf16* __restrict__ Bt,
                                          const float* __restrict__ bias,
                                          void* __restrict__ Cv,
                                          int M, int K, int Nstore,
                                          int bx, int by,
                                          __bf16* sA, __bf16* sB) {
    const int tid   = threadIdx.x;
    const int lane  = tid & 63;
    const int wave  = tid >> 6;
    const int wr    = wave >> 1;
    const int wc    = wave & 1;
    const int mBase = by * 128;
    const int nBase = bx * 128;
    const int lr    = lane >> 4;
    const int lc    = lane & 15;

    floatx4 acc[4][4];
#pragma unroll
    for (int i = 0; i < 4; ++i)
#pragma unroll
        for (int j = 0; j < 4; ++j) acc[i][j] = (floatx4)0.f;

    for (int k0 = 0; k0 < K; k0 += 64) {
#pragma unroll
        for (int it = 0; it < 4; ++it) {
            int lin = it * 256 + tid;
            int r   = lin >> 3;
            int kc  = (lin & 7) ^ (r & 7);          // XOR swizzle
            const __bf16* ga = A  + (size_t)(mBase + r) * K + k0 + kc * 8;
            const __bf16* gb = Bt + (size_t)(nBase + r) * K + k0 + kc * 8;
            __builtin_amdgcn_global_load_lds(
                (__attribute__((address_space(1))) void*)ga,
                (__attribute__((address_space(3))) void*)(sA + lin * 8), 16, 0, 0);
            __builtin_amdgcn_global_load_lds(
                (__attribute__((address_space(1))) void*)gb,
                (__attribute__((address_space(3))) void*)(sB + lin * 8), 16, 0, 0);
        }
        __builtin_amdgcn_s_waitcnt(0);
        __syncthreads();

#pragma unroll
        for (int kk = 0; kk < 2; ++kk) {
            const int sw = (kk * 4 + lr) ^ (lc & 7);   // swizzled chunk
            bf16x8 af[4], bfr[4];
#pragma unroll
            for (int i = 0; i < 4; ++i)
                af[i] = *(const bf16x8*)(sA + (wr * 64 + i * 16 + lc) * 64 + sw * 8);
#pragma unroll
            for (int j = 0; j < 4; ++j)
                bfr[j] = *(const bf16x8*)(sB + (wc * 64 + j * 16 + lc) * 64 + sw * 8);
#pragma unroll
            for (int i = 0; i < 4; ++i)
#pragma unroll
                for (int j = 0; j < 4; ++j)
                    acc[i][j] = __builtin_amdgcn_mfma_f32_16x16x32_bf16(af[i], bfr[j], acc[i][j], 0, 0, 0);
        }
        __syncthreads();
    }

#pragma unroll
    for (int j = 0; j < 4; ++j) {
        int col = nBase + wc * 64 + j * 16 + lc;
        if (col < Nstore) {
            float bv = bias[col];
#pragma unroll
            for (int i = 0; i < 4; ++i) {
                int rowb = mBase + wr * 64 + i * 16 + lr * 4;
#pragma unroll
                for (int r = 0; r < 4; ++r) {
                    float v = acc[i][j][r] + bv;
                    if (RELU) v = fmaxf(v, 0.f);
                    if (OUT_BF16)
                        ((__bf16*)Cv)[(size_t)(rowb + r) * Nstore + col] = (__bf16)v;
                    else
                        ((float*)Cv)[(size_t)(rowb + r) * Nstore + col] = v;
                }
            }
        }
    }
}

// ---------------------------------------------------------------------------
// prep1: blocks [0,4096) x f32->bf16 (2048 elem/block); [4096,6144) w1
// transpose ([2048][4096] -> w1t [4096][2048]). Whole-block branch.
// ---------------------------------------------------------------------------
__global__ __launch_bounds__(256) void prep1(const float* __restrict__ x,
                                             __bf16* __restrict__ xb,
                                             const float* __restrict__ w1,
                                             __bf16* __restrict__ w1t) {
    __shared__ float tile[64 * 65];
    const int b = blockIdx.x;
    if (b < 4096) {
        int i = (b * 256 + (int)threadIdx.x) * 8;
        float4 a = *(const float4*)(x + i);
        float4 c = *(const float4*)(x + i + 4);
        bf16x8 o;
        o[0] = (__bf16)a.x; o[1] = (__bf16)a.y; o[2] = (__bf16)a.z; o[3] = (__bf16)a.w;
        o[4] = (__bf16)c.x; o[5] = (__bf16)c.y; o[6] = (__bf16)c.z; o[7] = (__bf16)c.w;
        *(bf16x8*)(xb + i) = o;
    } else {
        int l = b - 4096;                       // 32 r-tiles x 64 c-tiles
        transpose_cvt_dev(w1, w1t, IN_, HID_, l & 31, l >> 5, tile);
    }
}

// ---------------------------------------------------------------------------
// gemm1_fused: blocks [0,1024) = layer-1 GEMM (XCD-swizzled tile mapping,
// fills all CUs immediately); [1024,5120) = w2 transpose; [5120,6144) = w3
// transpose (+zero-fill rows 1000..1023). Transposes (pure-memory) overlap
// the MFMA-bound GEMM; outputs consumed only by later dispatches.
// ---------------------------------------------------------------------------
__global__ __launch_bounds__(256, 2) void gemm1_fused(const __bf16* __restrict__ xb,
                                                      const __bf16* __restrict__ w1t,
                                                      const float* __restrict__ b1,
                                                      __bf16* __restrict__ h1,
                                                      const float* __restrict__ w2,
                                                      __bf16* __restrict__ w2t,
                                                      const float* __restrict__ w3,
                                                      __bf16* __restrict__ w3t) {
    __shared__ float smem[8192];                // 32 KB, shared by both roles
    const int b = blockIdx.x;
    if (b < 1024) {
        __bf16* sA = (__bf16*)smem;
        __bf16* sB = sA + 128 * 64;
        int bx, by;
        swizzle32x32(b, bx, by);
        gemm_core<true, true>(xb, w1t, b1, h1, B_, IN_, HID_, bx, by, sA, sB);
    } else if (b < 5120) {
        int l = b - 1024;                       // 64 x 64 tiles
        transpose_cvt_dev(w2, w2t, HID_, HID_, l & 63, l >> 6, smem);
    } else {
        int l = b - 5120;                       // 64 x 16 tiles
        transpose_cvt_dev(w3, w3t, HID_, NC_, l & 63, l >> 6, smem);
    }
}

// ===========================================================================
// Layer-2 GEMM: 256x256 tile, BK=64, 8 waves (2M x 4N), 4 phases/tile.
// REGISTER PHYSICS (R3/R4 post-mortem, binding constraint): 8-wave block =
// 2 waves/SIMD (geometry, not launch bounds); unified pool ~512 regs/SIMD
// -> 256 regs/wave total; acc = 128 -> ARCH-VGPR BUDGET <= ~128. R3/R4's
// 64-reg B double-buffer exceeded it -> ~30 regs spilled (FETCH 99->242 MB,
// MfmaUtil 16%). This kernel = R2's spill-free schedule (24 ds_reads/tile:
// B hoisted once, A m-pairs one phase ahead, counted LGKM 4/4/4/0) with two
// zero-register fixes:
//   1. NO TAIL: all 4 half-tile stages of tile t+1 issue at tile t's LEADER
//      into the other buffer. Safe: that buffer was read by tile t-1, and
//      every wave's P3 LGKM(0) precedes the end-of-tile barrier -> all its
//      reads retired block-wide before staging can issue.
//   2. Leader LGKM(4) covered by the 8 staging VMEM issues + addr VALU
//      placed between the 16 leader ds_reads and the wait.
// VMCNT(0) gate at leader drains staging issued one FULL tile (~4000 cyc)
// earlier -> free (the "never drain" rule targets fresh loads). Tile 0 pays
// full HBM latency once.
// ===========================================================================
#define PRIO1 __builtin_amdgcn_s_setprio(1)
#define PRIO0 __builtin_amdgcn_s_setprio(0)
#define BAR() __builtin_amdgcn_s_barrier()
#define LGKM(n)                                                  \
    asm volatile("s_waitcnt lgkmcnt(" #n ")" ::: "memory");      \
    __builtin_amdgcn_sched_barrier(0)
#define VMCNT(n) asm volatile("s_waitcnt vmcnt(" #n ")" ::: "memory")

// 4 ds_read_b128: A frags for m-pair {mb, mb+1}, kk=0..1 (mb literal).
#define LDA2(dst, mb, pA)                                                      \
    _Pragma("unroll") for (int mi_ = 0; mi_ < 2; ++mi_)                        \
    _Pragma("unroll") for (int kk_ = 0; kk_ < 2; ++kk_)                        \
        dst[mi_][kk_] = *(const bf16x8*)((pA) +                                \
            (wr * 128 + ((mb) + mi_) * 16 + lc) * 64 +                         \
            (((kk_ * 4) + lr) ^ (lc & 7)) * 8);

// 8 ds_read_b128: all B frags for the wave's 64-col strip, K=64.
#define LDB8(pB)                                                               \
    _Pragma("unroll") for (int n_ = 0; n_ < 4; ++n_)                           \
    _Pragma("unroll") for (int kk_ = 0; kk_ < 2; ++kk_)                        \
        bq[n_][kk_] = *(const bf16x8*)((pB) +                                  \
            (wc * 64 + n_ * 16 + lc) * 64 +                                    \
            (((kk_ * 4) + lr) ^ (lc & 7)) * 8);

// 16 MFMA: m-pair {mb,mb+1} x n=0..3 x kk chain (mb literal -> static acc idx).
#define MFMA16(aset, mb)                                                       \
    _Pragma("unroll") for (int mi_ = 0; mi_ < 2; ++mi_)                        \
    _Pragma("unroll") for (int n_ = 0; n_ < 4; ++n_) {                         \
        acc[(mb) + mi_][n_] = __builtin_amdgcn_mfma_f32_16x16x32_bf16(         \
            aset[mi_][0], bq[n_][0], acc[(mb) + mi_][n_], 0, 0, 0);            \
        acc[(mb) + mi_][n_] = __builtin_amdgcn_mfma_f32_16x16x32_bf16(         \
            aset[mi_][1], bq[n_][1], acc[(mb) + mi_][n_], 0, 0, 0);            \
    }

// Stage full K-tile kt (A 2 halves + B 2 halves, 8 global_load_lds/thread).
#define STAGE4(kt, base)                                                       \
    stage_half(A,  mBase,       (kt) * 64, (base));                            \
    stage_half(A,  mBase + 128, (kt) * 64, (base) + 8192);                     \
    stage_half(Bt, nBase,       (kt) * 64, (base) + 16384);                    \
    stage_half(Bt, nBase + 128, (kt) * 64, (base) + 24576);

// Steady tile: gate CUR, read+compute tile from CUR, stage tile ktS -> OTH
// at the leader (between leader ds_reads and LGKM -> latency cover).
#define TILE_S(CUR, OTH, ktS) {                                                \
    VMCNT(0);                       /* drains CUR staging: 1 tile old, free */ \
    BAR();                          /* publish CUR block-wide */               \
    const __bf16* pA_ = (CUR);                                                 \
    const __bf16* pB_ = (CUR) + 16384;                                         \
    bf16x8 bq[4][2], aX[2][2], aY[2][2];                                       \
    LDB8(pB_); LDA2(aX, 0, pA_); LDA2(aY, 2, pA_);   /* 16 ds_reads */         \
    STAGE4(ktS, OTH);               /* 8 VMEM issues cover the LGKM wait */    \
    LGKM(4);                                                                   \
    PRIO1; MFMA16(aX, 0); PRIO0; BAR();                                        \
    LDA2(aX, 4, pA_);                                                          \
    BAR(); LGKM(4); PRIO1; MFMA16(aY, 2); PRIO0; BAR();                        \
    LDA2(aY, 6, pA_);                                                          \
    BAR(); LGKM(4); PRIO1; MFMA16(aX, 4); PRIO0; BAR();                        \
    LGKM(0); PRIO1; MFMA16(aY, 6); PRIO0; BAR();   /* end fence: CUR free */   \
}

// Last tile: no staging.
#define TILE_L(CUR) {                                                          \
    VMCNT(0);                                                                  \
    BAR();                                                                     \
    const __bf16* pA_ = (CUR);                                                 \
    const __bf16* pB_ = (CUR) + 16384;                                         \
    bf16x8 bq[4][2], aX[2][2], aY[2][2];                                       \
    LDB8(pB_); LDA2(aX, 0, pA_); LDA2(aY, 2, pA_);                             \
    LGKM(4);                                                                   \
    PRIO1; MFMA16(aX, 0); PRIO0; BAR();                                        \
    LDA2(aX, 4, pA_);                                                          \
    BAR(); LGKM(4); PRIO1; MFMA16(aY, 2); PRIO0; BAR();                        \
    LDA2(aY, 6, pA_);                                                          \
    BAR(); LGKM(4); PRIO1; MFMA16(aX, 4); PRIO0; BAR();                        \
    LGKM(0); MFMA16(aY, 6);                                                    \
}

__global__ __launch_bounds__(512, 1) void gemm2_256(const __bf16* __restrict__ A,
                                                    const __bf16* __restrict__ Bt,
                                                    const float* __restrict__ bias,
                                                    __bf16* __restrict__ C) {
    extern __shared__ __bf16 lds[];             // 65536 bf16 = 128 KiB
    const int tid  = threadIdx.x;
    const int lane = tid & 63;
    const int wave = tid >> 6;
    const int wr   = wave >> 2;                 // 0..1  (M)
    const int wc   = wave & 3;                  // 0..3  (N)
    const int lr   = lane >> 4;                 // 0..3
    const int lc   = lane & 15;

    // T1: XCD-aware swizzle of the 16x16 tile grid (256 blocks, %8 == 0).
    int bid = blockIdx.y * 16 + blockIdx.x;
    int xcd = bid & 7, q = bid >> 3;            // q: 0..31
    const int by = (xcd & 3) * 4 + (q & 3);     // 0..15
    const int bx = (xcd >> 2) * 8 + (q >> 2);   // 0..15
    const int mBase = by * 256;
    const int nBase = bx * 256;

    // LDS: S0 { A [0,16384) | B [16384,32768) }, S1 { +32768 }.
    // Tile t's data lives in buf[t&1].
    __bf16* const S0p = lds;
    __bf16* const S1p = lds + 32768;

    // Stage one 128-row half (16 KB): 2 global_load_lds per thread.
    // Verified XOR chunk swizzle: slot c of row r holds global chunk c^(r&7).
    auto stage_half = [&](const __bf16* __restrict__ src, int rowBase, int k0,
                          __bf16* dst) {
#pragma unroll
        for (int it = 0; it < 2; ++it) {
            int lin = it * 512 + tid;           // 0..1023
            int rl  = lin >> 3;                 // 0..127
            int kc  = (lin & 7) ^ (rl & 7);
            const __bf16* gp = src + (size_t)(rowBase + rl) * HID_ + k0 + kc * 8;
            __builtin_amdgcn_global_load_lds(
                (__attribute__((address_space(1))) void*)gp,
                (__attribute__((address_space(3))) void*)(dst + lin * 8), 16, 0, 0);
        }
    };

    floatx4 acc[8][4];
#pragma unroll
    for (int i = 0; i < 8; ++i)
#pragma unroll
        for (int j = 0; j < 4; ++j) acc[i][j] = (floatx4)0.f;

    // Prologue: stage tile 0 only; tile t's leader stages tile t+1.
    STAGE4(0, S0p);

    for (int t = 0; t < 62; t += 2) {
        TILE_S(S0p, S1p, t + 1);                // tile t
        TILE_S(S1p, S0p, t + 2);                // tile t+1
    }
    TILE_S(S0p, S1p, 63);                       // tile 62 (stages tile 63)
    TILE_L(S1p);                                // tile 63

    // Epilogue: bias + ReLU + bf16 store (h2).
#pragma unroll
    for (int n = 0; n < 4; ++n) {
        int col = nBase + wc * 64 + n * 16 + lc;
        float bv = bias[col];
#pragma unroll
        for (int m = 0; m < 8; ++m) {
            int rowb = mBase + wr * 128 + m * 16 + lr * 4;
#pragma unroll
            for (int r = 0; r < 4; ++r) {
                float v = fmaxf(acc[m][n][r] + bv, 0.f);
                C[(size_t)(rowb + r) * HID_ + col] = (__bf16)v;
            }
        }
    }
}

// ---------------------------------------------------------------------------
// Layer-3 split-K x2 (512 blocks = 2/CU): P[z][M][1024] = partial GEMM.
// ---------------------------------------------------------------------------
__global__ __launch_bounds__(256, 2) void gemm_sk(const __bf16* __restrict__ A,
                                                  const __bf16* __restrict__ Bt,
                                                  float* __restrict__ P,
                                                  int M, int KH, int Ktot) {
    __shared__ __bf16 sA[128 * 64];
    __shared__ __bf16 sB[128 * 64];

    const int tid   = threadIdx.x;
    const int lane  = tid & 63;
    const int wave  = tid >> 6;
    const int wr    = wave >> 1;
    const int wc    = wave & 1;
    const int mBase = blockIdx.y * 128;
    const int nBase = blockIdx.x * 128;
    const int z     = blockIdx.z;
    const int kOff  = z * KH;
    const int lr    = lane >> 4;
    const int lc    = lane & 15;

    floatx4 acc[4][4];
#pragma unroll
    for (int i = 0; i < 4; ++i)
#pragma unroll
        for (int j = 0; j < 4; ++j) acc[i][j] = (floatx4)0.f;

    for (int k0 = kOff; k0 < kOff + KH; k0 += 64) {
#pragma unroll
        for (int it = 0; it < 4; ++it) {
            int lin = it * 256 + tid;
            int r   = lin >> 3;
            int kc  = (lin & 7) ^ (r & 7);
            const __bf16* ga = A  + (size_t)(mBase + r) * Ktot + k0 + kc * 8;
            const __bf16* gb = Bt + (size_t)(nBase + r) * Ktot + k0 + kc * 8;
            __builtin_amdgcn_global_load_lds(
                (__attribute__((address_space(1))) void*)ga,
                (__attribute__((address_space(3))) void*)(sA + lin * 8), 16, 0, 0);
            __builtin_amdgcn_global_load_lds(
                (__attribute__((address_space(1))) void*)gb,
                (__attribute__((address_space(3))) void*)(sB + lin * 8), 16, 0, 0);
        }
        __builtin_amdgcn_s_waitcnt(0);
        __syncthreads();

#pragma unroll
        for (int kk = 0; kk < 2; ++kk) {
            const int sw = (kk * 4 + lr) ^ (lc & 7);
            bf16x8 af[4], bfr[4];
#pragma unroll
            for (int i = 0; i < 4; ++i)
                af[i] = *(const bf16x8*)(sA + (wr * 64 + i * 16 + lc) * 64 + sw * 8);
#pragma unroll
            for (int j = 0; j < 4; ++j)
                bfr[j] = *(const bf16x8*)(sB + (wc * 64 + j * 16 + lc) * 64 + sw * 8);
#pragma unroll
            for (int i = 0; i < 4; ++i)
#pragma unroll
                for (int j = 0; j < 4; ++j)
                    acc[i][j] = __builtin_amdgcn_mfma_f32_16x16x32_bf16(af[i], bfr[j], acc[i][j], 0, 0, 0);
        }
        __syncthreads();
    }

    float* Pz = P + (size_t)z * M * NCP_;
#pragma unroll
    for (int j = 0; j < 4; ++j) {
        int col = nBase + wc * 64 + j * 16 + lc;
#pragma unroll
        for (int i = 0; i < 4; ++i) {
            int rowb = mBase + wr * 64 + i * 16 + lr * 4;
#pragma unroll
            for (int r = 0; r < 4; ++r)
                Pz[(size_t)(rowb + r) * NCP_ + col] = acc[i][j][r];
        }
    }
}

// ---------------------------------------------------------------------------
// out[m][c] = P0[m][c] + P1[m][c] + b3[c], c < 1000. grid (4, 4096).
// ---------------------------------------------------------------------------
__global__ __launch_bounds__(256) void reduce_bias(const float* __restrict__ P,
                                                   const float* __restrict__ b3,
                                                   float* __restrict__ out) {
    int c = blockIdx.x * 256 + threadIdx.x;
    int m = blockIdx.y;
    if (c < NC_)
        out[(size_t)m * NC_ + c] =
            P[(size_t)m * NCP_ + c] + P[(size_t)(B_ + m) * NCP_ + c] + b3[c];
}

extern "C" void kernel_launch(void* const* d_in, const int* in_sizes, int n_in,
                              void* d_out, int out_size, void* d_ws, size_t ws_size,
                              hipStream_t stream) {
    const float* x  = (const float*)d_in[0];
    const float* w1 = (const float*)d_in[1];
    const float* b1 = (const float*)d_in[2];
    const float* w2 = (const float*)d_in[3];
    const float* b2 = (const float*)d_in[4];
    const float* w3 = (const float*)d_in[5];
    const float* b3 = (const float*)d_in[6];
    float* out = (float*)d_out;

    // ws (MiB): [0,16) xb | [16,32) w1t | [32,64) w2t | [64,72) w3t |
    // [72,104) h1. h2 aliases [0,32) (xb/w1t dead after gemm1);
    // split-K partials P alias [72,104) (h1 dead after gemm2). 104 MiB.
    char* ws = (char*)d_ws;
    __bf16* xb  = (__bf16*)(ws);
    __bf16* w1t = (__bf16*)(ws + (16u << 20));
    __bf16* w2t = (__bf16*)(ws + (32u << 20));
    __bf16* w3t = (__bf16*)(ws + (64u << 20));
    __bf16* h1  = (__bf16*)(ws + (72u << 20));
    __bf16* h2  = (__bf16*)(ws);
    float*  P   = (float*)(ws + (72u << 20));

    // 128 KiB dynamic LDS for gemm2_256.
    static int attr_done = 0;
    if (!attr_done) {
        (void)hipFuncSetAttribute((const void*)gemm2_256,
                                  hipFuncAttributeMaxDynamicSharedMemorySize,
                                  131072);
        attr_done = 1;
    }

    prep1<<<6144, 256, 0, stream>>>(x, xb, w1, w1t);

    gemm1_fused<<<6144, 256, 0, stream>>>(xb, w1t, b1, h1, w2, w2t, w3, w3t);

    gemm2_256<<<dim3(16, 16), 512, 131072, stream>>>(h1, w2t, b2, h2);

    gemm_sk<<<dim3(NCP_ / 128, B_ / 128, 2), 256, 0, stream>>>(
        h2, w3t, P, B_, HID_ / 2, HID_);
    reduce_bias<<<dim3(NCP_ / 256, B_), 256, 0, stream>>>(P, b3, out);
}